// Round 3
// baseline (3374.355 us; speedup 1.0000x reference)
//
#include <hip/hip_runtime.h>
#include <cmath>
#include <cstdint>

// B=64, NH=256, T=4096, KS=5, STRIDE=2, DEPTH_VARIANT (Cin1=257), 12 depths.
// bf16-MFMA GEMM formulation with hi/lo split (3 mfma) for fp32-level accuracy.
// Activations channels-last rows: [b][t] -> 1024B = 256 bf16 hi | 256 bf16 lo.
// l stored fp32 channels-last rows (1024B); conv2 overwrites them with h in place.
// Round 6: (1) 8-way SHARDED work queue — round-5's single atomic counter
// serialized ~25K pops (light-item drain = pure pop storms; d2 conv1: 2048 pops
// ~ 55us vs ~50us of work) costing ~500us total. Shard q (blockIdx.x&7) owns
// items == q mod 8 (same x-major heavy-first order), counters 128B apart:
// same greedy balance, 1/8 the per-line traffic. (2) launch_bounds(256,3):
// round-5 counters showed VGPR=64 + 64 AGPR acc = exactly the 128-reg unified-
// file cap of (256,4) -> zero pipelining headroom, latency-bound inner loop
// (MFMA issue ~8% of wall). Cap ~170 lets the scheduler hoist next-chunk
// A/B loads; 3 blocks/CU x 34KB LDS = 103KB fits.

typedef __attribute__((ext_vector_type(8))) __bf16 bf16x8;
typedef __attribute__((ext_vector_type(4))) float f32x4;

union U16B { uint4 u; bf16x8 b; };
__device__ __forceinline__ bf16x8 as_bf16x8(uint4 u) { U16B x; x.u = u; return x.b; }

__device__ __forceinline__ unsigned short bf_hi_bits(float x) {
    union { __bf16 b; unsigned short s; } u; u.b = (__bf16)x; return u.s;
}
__device__ __forceinline__ float bf_hi_f(float x) { return (float)(__bf16)x; }

#define MFMA(a, b, c) __builtin_amdgcn_mfma_f32_16x16x32_bf16(a, b, c, 0, 0, 0)

// ---------------- setup: finish_depth + stable argsort rank + queue zero ----
// ctrs: 24 kernel slots x 8 shards x 32 ints (128B shard stride) = 6144 ints.
__global__ void setup_kernel(const int* __restrict__ N0, int* __restrict__ rankfd,
                             int* __restrict__ ctrs) {
    __shared__ int fd_s[64];
    int b = threadIdx.x;
    for (int i = b; i < 24 * 256; i += 64) ctrs[i] = 0;
    int n = N0[b];
    int d = 0;
    while ((1 << (d + 1)) < n) ++d;   // first d with N0 <= 2^(d+1)
    fd_s[b] = d;
    __syncthreads();
    int myfd = fd_s[b];
    int r = 0;
    for (int i = 0; i < 64; ++i) {
        int f = fd_s[i];
        r += (f < myfd || (f == myfd && i < b)) ? 1 : 0;
    }
    rankfd[b] = r;
    rankfd[64 + b] = myfd;
}

// ------------- prepack: weights into MFMA A-fragment order, hi/lo ----------
// W*[chunk][ot][lane][j]; chunk = k*8+cc (c = cc*32 + (lane>>4)*8 + j),
// oc = ot*16 + (lane&15). conv1: OT=32 (512 oc), conv2: OT=16.
__global__ void prepack_kernel(const float* __restrict__ w1, const float* __restrict__ w2,
                               unsigned short* __restrict__ Whi1, unsigned short* __restrict__ Wlo1,
                               unsigned short* __restrict__ Whi2, unsigned short* __restrict__ Wlo2,
                               float* __restrict__ wd1, float* __restrict__ wsum1) {
    const int T1 = 40 * 32 * 512;
    const int T2 = 40 * 16 * 512;
    int id = blockIdx.x * 256 + threadIdx.x;
    if (id < T1) {
        int chunk = id >> 14;
        int rem = id & 16383;
        int ot = rem >> 9;
        int rem2 = rem & 511;
        int l = rem2 >> 3, j = rem2 & 7;
        int k = chunk >> 3, cc = chunk & 7;
        int oc = ot * 16 + (l & 15);
        int c = cc * 32 + (l >> 4) * 8 + j;
        float wv = w1[oc * 1285 + c * 5 + k];
        Whi1[id] = bf_hi_bits(wv);
        Wlo1[id] = bf_hi_bits(wv - bf_hi_f(wv));
    } else if (id < T1 + T2) {
        int base = id - T1;
        int chunk = base >> 13;
        int rem = base & 8191;
        int ot = rem >> 9;
        int rem2 = rem & 511;
        int l = rem2 >> 3, j = rem2 & 7;
        int k = chunk >> 3, cc = chunk & 7;
        int oc = ot * 16 + (l & 15);
        int c = cc * 32 + (l >> 4) * 8 + j;
        float wv = w2[oc * 1280 + c * 5 + k];
        Whi2[base] = bf_hi_bits(wv);
        Wlo2[base] = bf_hi_bits(wv - bf_hi_f(wv));
    } else if (id < T1 + T2 + 512) {
        int oc = id - T1 - T2;         // depth-channel weights (c = 256)
        float s = 0.f;
        for (int k = 0; k < 5; ++k) {
            float wv = w1[oc * 1285 + 1280 + k];
            wd1[oc * 5 + k] = wv;
            s += wv;
        }
        wsum1[oc] = s;
    }
}

// ---- transpose h [B][256][4096] fp32 (masked) -> channels-last hi/lo rows ----
__global__ __launch_bounds__(256, 4)
void transpose_kernel(const float* __restrict__ h, const int* __restrict__ N0,
                      char* __restrict__ H) {
    __shared__ unsigned short sm[2 * 64 * 140];   // 35840 B
    const int tid = threadIdx.x;
    const int b = blockIdx.z;
    const int c0 = blockIdx.y * 64;
    const int t0 = blockIdx.x * 128;
    const int n0 = N0[b];
    const int lane32 = tid & 31;
    // read phase
    for (int it = 0; it < 8; ++it) {
        int cl = (tid >> 5) * 8 + it;
        const float* src = h + ((size_t)(b * 256 + c0 + cl)) * 4096 + t0 + lane32 * 4;
        float4 v = *(const float4*)src;
        int gt = t0 + lane32 * 4;
        float f[4] = {v.x, v.y, v.z, v.w};
        ushort4 hi, lo;
        unsigned short* hp = &hi.x;
        unsigned short* lp = &lo.x;
#pragma unroll
        for (int e = 0; e < 4; ++e) {
            float x = (gt + e < n0) ? f[e] : 0.f;
            float xh = bf_hi_f(x);
            hp[e] = bf_hi_bits(x);
            lp[e] = bf_hi_bits(x - xh);
        }
        *(ushort4*)(&sm[cl * 140 + lane32 * 4]) = hi;
        *(ushort4*)(&sm[8960 + cl * 140 + lane32 * 4]) = lo;
    }
    __syncthreads();
    // write phase
    const int sub = tid & 7;
    const int rowp = tid >> 3;
    for (int rep = 0; rep < 8; ++rep) {
        int idx = rowp + 32 * rep;      // 0..255
        int tl = idx >> 1;
        int plane = idx & 1;
        union { unsigned short s[8]; uint4 u; } pk;
#pragma unroll
        for (int j = 0; j < 8; ++j)
            pk.s[j] = sm[plane * 8960 + (sub * 8 + j) * 140 + tl];
        char* dst = H + ((size_t)(b * 4096) + t0 + tl) * 1024 + plane * 512 + c0 * 2 + sub * 16;
        *(uint4*)dst = pk.u;
    }
}

// ---------------- conv1: lr = conv(hh_masked, w1, stride 2) ----------------
// Persistent, 8-way sharded queue: shard q = blockIdx.x&7 owns items == q mod 8
// of item = x*128 + y*64 + b (x-major: heavy-first). Tile 256 oc (y) x 64 t.
// K staged in 4 c-quarters (64 ch hi+lo, 132 rows x 256B = 33.8 KB LDS).
__global__ __launch_bounds__(256, 3)
void conv1_kernel(const char* __restrict__ Hin,
                  const unsigned short* __restrict__ Whi, const unsigned short* __restrict__ Wlo,
                  const float* __restrict__ b1, const float* __restrict__ wd1,
                  const float* __restrict__ wsum1, const int* __restrict__ N0,
                  float* __restrict__ Lout, char* __restrict__ Rout,
                  int T_in, int T_out, int depth, float logd,
                  int* __restrict__ ctr, int NI) {
    __shared__ __align__(16) char smem[132 * 256];
    __shared__ int s_it;
    const int tid = threadIdx.x;
    const int w = tid >> 6, l = tid & 63;
    const int qid = blockIdx.x & 7;
    int* my_ctr = ctr + qid * 32;       // 128B shard stride
    // staging decomposition: 16 chunks/row (8 hi + 8 lo of this quarter)
    const int sg_g8 = l & 7;
    const int sg_seg = (l >> 3) & 1;
    const int sg_rb0 = tid >> 4;        // 0..15

    for (;;) {
        if (tid == 0) s_it = qid + 8 * atomicAdd(my_ctr, 1);
        __syncthreads();
        const int item = s_it;
        __syncthreads();                 // WAR fence on s_it + cross-item LDS fence
        if (item >= NI) break;

        const int b = item & 63;
        const int y = (item >> 6) & 1;
        const int t0 = (item >> 7) * 64;
        const int n0 = N0[b];
        const int Nb = (n0 + (1 << depth) - 1) >> depth;   // input mask len
        const int Nn = (Nb + 1) >> 1;                      // output mask len

        if (t0 >= Nn) {
            if (y == 1) {   // zero r rows (conv2 reads them in its halo)
                int row = t0 + (tid >> 2);
                if (row < T_out) {
                    char* rp = Rout + ((size_t)(b * T_out) + row) * 1024 + (tid & 3) * 256;
                    uint4 z = make_uint4(0, 0, 0, 0);
#pragma unroll
                    for (int qq = 0; qq < 16; ++qq) *(uint4*)(rp + qq * 16) = z;
                }
            }
            continue;
        }

        f32x4 acc[4][4];
#pragma unroll
        for (int i = 0; i < 4; ++i)
#pragma unroll
            for (int j = 0; j < 4; ++j) acc[i][j] = f32x4{0.f, 0.f, 0.f, 0.f};

        const int base_p = 2 * t0 - 2;
        const int otg_base = y * 16 + w * 4;

#pragma unroll 1
        for (int q0 = 0; q0 < 4; ++q0) {
            if (q0) __syncthreads();
            for (int rb = sg_rb0; rb < 132; rb += 16) {
                int p = base_p + rb;
                uint4 v = make_uint4(0, 0, 0, 0);
                if (p >= 0 && p < T_in)
                    v = *(const uint4*)(Hin + ((size_t)(b * T_in) + p) * 1024 + sg_seg * 512 + q0 * 128 + sg_g8 * 16);
                int s = (rb >> 1) + (rb & 1) * 66;   // even/odd split for stride-2
                int phys = (sg_g8 ^ (s & 7)) | (sg_seg << 3);
                *(uint4*)(smem + s * 256 + phys * 16) = v;
            }
            __syncthreads();
#pragma unroll
            for (int k = 0; k < 5; ++k) {
#pragma unroll
                for (int ccl = 0; ccl < 2; ++ccl) {
                    const int chunk = k * 8 + q0 * 2 + ccl;
                    bf16x8 Bh[4], Bl[4];
#pragma unroll
                    for (int tt = 0; tt < 4; ++tt) {
                        int s = tt * 16 + (l & 15) + (k >> 1) + (k & 1) * 66;
                        int gB = ccl * 4 + (l >> 4);
                        int ph = gB ^ (s & 7);
                        Bh[tt] = as_bf16x8(*(const uint4*)(smem + s * 256 + ph * 16));
                        Bl[tt] = as_bf16x8(*(const uint4*)(smem + s * 256 + (ph | 8) * 16));
                    }
#pragma unroll
                    for (int ot = 0; ot < 4; ++ot) {
                        size_t aoff = ((size_t)(chunk * 32 + otg_base + ot)) * 512 + l * 8;
                        bf16x8 Ah = as_bf16x8(*(const uint4*)(Whi + aoff));
                        bf16x8 Al = as_bf16x8(*(const uint4*)(Wlo + aoff));
#pragma unroll
                        for (int tt = 0; tt < 4; ++tt) {
                            acc[ot][tt] = MFMA(Ah, Bh[tt], acc[ot][tt]);
                            acc[ot][tt] = MFMA(Ah, Bl[tt], acc[ot][tt]);
                            acc[ot][tt] = MFMA(Al, Bh[tt], acc[ot][tt]);
                        }
                    }
                }
            }
        }

        // ---- epilogue ----
        const int q = l >> 4;
        const int n = l & 15;
        const bool is_r = (y == 1);
#pragma unroll
        for (int ot = 0; ot < 4; ++ot) {
            const int ocg0 = (otg_base + ot) * 16 + q * 4;   // global oc (0..511)
            float4 bias = *(const float4*)(b1 + ocg0);
            float4 ws4 = *(const float4*)(wsum1 + ocg0);
#pragma unroll
            for (int tt = 0; tt < 4; ++tt) {
                int t = t0 + tt * 16 + n;
                if (t >= T_out) continue;
                float v0 = acc[ot][tt].x, v1 = acc[ot][tt].y, v2 = acc[ot][tt].z, v3 = acc[ot][tt].w;
                if (depth > 0) {   // depth channel (constant log1p(depth), masked)
                    if (t >= 1 && 2 * t + 2 < Nb) {
                        v0 += logd * ws4.x; v1 += logd * ws4.y;
                        v2 += logd * ws4.z; v3 += logd * ws4.w;
                    } else {
                        float ind[5];
#pragma unroll
                        for (int k = 0; k < 5; ++k) {
                            int p = 2 * t + k - 2;
                            ind[k] = (p >= 0 && p < Nb) ? logd : 0.f;
                        }
                        float sv[4] = {0.f, 0.f, 0.f, 0.f};
#pragma unroll
                        for (int j = 0; j < 4; ++j)
#pragma unroll
                            for (int k = 0; k < 5; ++k) sv[j] += ind[k] * wd1[(ocg0 + j) * 5 + k];
                        v0 += sv[0]; v1 += sv[1]; v2 += sv[2]; v3 += sv[3];
                    }
                }
                v0 += bias.x; v1 += bias.y; v2 += bias.z; v3 += bias.w;
                if (!is_r) {
                    float4 o; o.x = v0; o.y = v1; o.z = v2; o.w = v3;
                    *(float4*)(Lout + ((size_t)(b * T_out) + t) * 256 + ocg0) = o;
                } else {
                    bool live = (t < Nn);
                    float r0v = live ? fmaxf(v0, 0.f) : 0.f;
                    float r1v = live ? fmaxf(v1, 0.f) : 0.f;
                    float r2v = live ? fmaxf(v2, 0.f) : 0.f;
                    float r3v = live ? fmaxf(v3, 0.f) : 0.f;
                    int ocr = ocg0 - 256;
                    char* rrow = Rout + ((size_t)(b * T_out) + t) * 1024;
                    ushort4 H, L2;
                    H.x = bf_hi_bits(r0v); L2.x = bf_hi_bits(r0v - bf_hi_f(r0v));
                    H.y = bf_hi_bits(r1v); L2.y = bf_hi_bits(r1v - bf_hi_f(r1v));
                    H.z = bf_hi_bits(r2v); L2.z = bf_hi_bits(r2v - bf_hi_f(r2v));
                    H.w = bf_hi_bits(r3v); L2.w = bf_hi_bits(r3v - bf_hi_f(r3v));
                    *(ushort4*)(rrow + ocr * 2) = H;
                    *(ushort4*)(rrow + 512 + ocr * 2) = L2;
                }
            }
        }
    }
}

// ------------- conv2: h = relu(l + conv(r, w2, 1) + b2), in-place ----------
// Persistent, 8-way sharded queue over item = x*64 + b; tile 256 oc x 64 t;
// K staged in 2 c-halves (68 rows x 512B = 34.8 KB LDS).
__global__ __launch_bounds__(256, 3)
void conv2_kernel(const char* __restrict__ Rin,
                  const unsigned short* __restrict__ Whi, const unsigned short* __restrict__ Wlo,
                  const float* __restrict__ b2, const int* __restrict__ N0,
                  const int* __restrict__ rankfd, float* __restrict__ LH,
                  float* __restrict__ out, int T, int depth,
                  int* __restrict__ ctr, int NI) {
    __shared__ __align__(16) char smem[68 * 512];
    __shared__ int s_it;
    const int tid = threadIdx.x;
    const int w = tid >> 6, l = tid & 63;
    const int qid = blockIdx.x & 7;
    int* my_ctr = ctr + qid * 32;       // 128B shard stride
    const int sg_g16 = l & 15;
    const int sg_seg = (l >> 4) & 1;
    const int sg_rb0 = w * 2 + (l >> 5);

    for (;;) {
        if (tid == 0) s_it = qid + 8 * atomicAdd(my_ctr, 1);
        __syncthreads();
        const int item = s_it;
        __syncthreads();                 // WAR fence on s_it + cross-item LDS fence
        if (item >= NI) break;

        const int b = item & 63;
        const int t0 = (item >> 6) * 64;
        const int n0 = N0[b];
        const int Nn = (n0 + (1 << (depth + 1)) - 1) >> (depth + 1);

        if (t0 >= Nn) {   // h rows are zero here; next conv1 reads them
            int row = t0 + (tid >> 2);
            if (row < T) {
                char* hp = (char*)LH + ((size_t)(b * T) + row) * 1024 + (tid & 3) * 256;
                uint4 z = make_uint4(0, 0, 0, 0);
#pragma unroll
                for (int qq = 0; qq < 16; ++qq) *(uint4*)(hp + qq * 16) = z;
            }
            continue;
        }

        f32x4 acc[4][4];
#pragma unroll
        for (int i = 0; i < 4; ++i)
#pragma unroll
            for (int j = 0; j < 4; ++j) acc[i][j] = f32x4{0.f, 0.f, 0.f, 0.f};

#pragma unroll 1
        for (int hf = 0; hf < 2; ++hf) {
            if (hf) __syncthreads();
            for (int rb = sg_rb0; rb < 68; rb += 8) {
                int p = t0 - 2 + rb;
                uint4 v = make_uint4(0, 0, 0, 0);
                if (p >= 0 && p < T)
                    v = *(const uint4*)(Rin + ((size_t)(b * T) + p) * 1024 + sg_seg * 512 + hf * 256 + sg_g16 * 16);
                int phys = (sg_g16 ^ (rb & 7)) | (sg_seg << 4);
                *(uint4*)(smem + rb * 512 + phys * 16) = v;
            }
            __syncthreads();
#pragma unroll
            for (int k = 0; k < 5; ++k) {
#pragma unroll
                for (int cc = 0; cc < 4; ++cc) {
                    const int chunk = k * 8 + hf * 4 + cc;
                    bf16x8 Bh[4], Bl[4];
#pragma unroll
                    for (int tt = 0; tt < 4; ++tt) {
                        int s = tt * 16 + (l & 15) + k;
                        int gq = cc * 4 + (l >> 4);
                        int ph = gq ^ (s & 7);
                        Bh[tt] = as_bf16x8(*(const uint4*)(smem + s * 512 + ph * 16));
                        Bl[tt] = as_bf16x8(*(const uint4*)(smem + s * 512 + (ph | 16) * 16));
                    }
#pragma unroll
                    for (int ot = 0; ot < 4; ++ot) {
                        size_t aoff = ((size_t)(chunk * 16 + w * 4 + ot)) * 512 + l * 8;
                        bf16x8 Ah = as_bf16x8(*(const uint4*)(Whi + aoff));
                        bf16x8 Al = as_bf16x8(*(const uint4*)(Wlo + aoff));
#pragma unroll
                        for (int tt = 0; tt < 4; ++tt) {
                            acc[ot][tt] = MFMA(Ah, Bh[tt], acc[ot][tt]);
                            acc[ot][tt] = MFMA(Ah, Bl[tt], acc[ot][tt]);
                            acc[ot][tt] = MFMA(Al, Bh[tt], acc[ot][tt]);
                        }
                    }
                }
            }
        }

        // ---- epilogue: l + acc + bias, relu, mask, capture; barrier; in-place h ----
        const int q = l >> 4;
        const int n = l & 15;
        const int rk = rankfd[b];
        const int fd = rankfd[64 + b];
#pragma unroll
        for (int ot = 0; ot < 4; ++ot) {
            const int ocg0 = (w * 4 + ot) * 16 + q * 4;
            float4 bias = *(const float4*)(b2 + ocg0);
#pragma unroll
            for (int tt = 0; tt < 4; ++tt) {
                int t = t0 + tt * 16 + n;
                float v0 = 0.f, v1 = 0.f, v2 = 0.f, v3 = 0.f;
                if (t < T && t < Nn) {
                    float4 l4 = *(const float4*)(LH + ((size_t)(b * T) + t) * 256 + ocg0);
                    v0 = fmaxf(acc[ot][tt].x + l4.x + bias.x, 0.f);
                    v1 = fmaxf(acc[ot][tt].y + l4.y + bias.y, 0.f);
                    v2 = fmaxf(acc[ot][tt].z + l4.z + bias.z, 0.f);
                    v3 = fmaxf(acc[ot][tt].w + l4.w + bias.w, 0.f);
                    if (t == 0 && depth == fd) {
                        float4 o; o.x = v0; o.y = v1; o.z = v2; o.w = v3;
                        *(float4*)(out + rk * 256 + ocg0) = o;
                    }
                }
                acc[ot][tt] = f32x4{v0, v1, v2, v3};   // reuse acc as value buffer
            }
        }
        __syncthreads();   // all l-reads complete before in-place overwrite
#pragma unroll
        for (int ot = 0; ot < 4; ++ot) {
            const int ocg0 = (w * 4 + ot) * 16 + q * 4;
#pragma unroll
            for (int tt = 0; tt < 4; ++tt) {
                int t = t0 + tt * 16 + n;
                if (t >= T) continue;
                char* hrow = (char*)LH + ((size_t)(b * T) + t) * 1024;
                float v0 = acc[ot][tt].x, v1 = acc[ot][tt].y, v2 = acc[ot][tt].z, v3 = acc[ot][tt].w;
                ushort4 H, L2;
                H.x = bf_hi_bits(v0); L2.x = bf_hi_bits(v0 - bf_hi_f(v0));
                H.y = bf_hi_bits(v1); L2.y = bf_hi_bits(v1 - bf_hi_f(v1));
                H.z = bf_hi_bits(v2); L2.z = bf_hi_bits(v2 - bf_hi_f(v2));
                H.w = bf_hi_bits(v3); L2.w = bf_hi_bits(v3 - bf_hi_f(v3));
                *(ushort4*)(hrow + ocg0 * 2) = H;
                *(ushort4*)(hrow + 512 + ocg0 * 2) = L2;
            }
        }
    }
}

// --------------------------------- launch ----------------------------------
extern "C" void kernel_launch(void* const* d_in, const int* in_sizes, int n_in,
                              void* d_out, int out_size, void* d_ws, size_t ws_size,
                              hipStream_t stream) {
    const float* h  = (const float*)d_in[0];
    const int*   N0 = (const int*)d_in[1];
    const float* w1 = (const float*)d_in[2];
    const float* b1 = (const float*)d_in[3];
    const float* w2 = (const float*)d_in[4];
    const float* b2 = (const float*)d_in[5];
    float* out = (float*)d_out;

    char* ws = (char*)d_ws;
    size_t off = 0;
    auto alloc = [&](size_t bytes) -> void* {
        void* p = ws + off;
        off = (off + bytes + 255) & ~(size_t)255;
        return p;
    };
    int* rankfd            = (int*)alloc(512);
    float* wd1             = (float*)alloc(512 * 5 * 4);
    float* wsum1           = (float*)alloc(512 * 4);
    unsigned short* Whi1   = (unsigned short*)alloc((size_t)655360 * 2);
    unsigned short* Wlo1   = (unsigned short*)alloc((size_t)655360 * 2);
    unsigned short* Whi2   = (unsigned short*)alloc((size_t)327680 * 2);
    unsigned short* Wlo2   = (unsigned short*)alloc((size_t)327680 * 2);
    float* P1              = (float*)alloc((size_t)64 * 2048 * 1024);   // even-depth h rows
    char*  H4096           = (char*)alloc((size_t)64 * 4096 * 1024);   // depth-0 input
    float* P0              = (float*)H4096;   // alias: H4096 dead after d0 conv1
    char*  R               = (char*)alloc((size_t)64 * 2048 * 1024);
    int* ctrs              = (int*)alloc((size_t)24 * 256 * 4);   // 24 slots x 8 shards x 128B
    (void)ws_size;

    setup_kernel<<<1, 64, 0, stream>>>(N0, rankfd, ctrs);
    {
        int total = 655360 + 327680 + 512;
        prepack_kernel<<<(total + 255) / 256, 256, 0, stream>>>(w1, w2, Whi1, Wlo1, Whi2, Wlo2, wd1, wsum1);
    }
    transpose_kernel<<<dim3(32, 4, 64), 256, 0, stream>>>(h, N0, H4096);

    int T_in = 4096;
    for (int d = 0; d < 12; ++d) {
        int To = T_in >> 1;
        float* LH = (d & 1) ? P0 : P1;
        const char* Hin = (d == 0) ? (const char*)H4096 : (const char*)((d & 1) ? P1 : P0);
        float logd = log1pf((float)d);
        int gx = (To + 63) / 64;
        int NI1 = gx * 128;                       // x-major: heavy-first, light tail
        int NI2 = gx * 64;
        int g1 = NI1 < 1024 ? NI1 : 1024;         // persistent blocks
        int g2 = NI2 < 1024 ? NI2 : 1024;
        conv1_kernel<<<g1, 256, 0, stream>>>(Hin, Whi1, Wlo1, b1, wd1, wsum1, N0,
                                             LH, R, T_in, To, d, logd,
                                             ctrs + (2 * d) * 256, NI1);
        conv2_kernel<<<g2, 256, 0, stream>>>(R, Whi2, Wlo2, b2, N0, rankfd, LH, out, To, d,
                                             ctrs + (2 * d + 1) * 256, NI2);
        T_in = To;
    }
}

// Round 4
// 3358.349 us; speedup vs baseline: 1.0048x; 1.0048x over previous
//
#include <hip/hip_runtime.h>
#include <cmath>
#include <cstdint>

// B=64, NH=256, T=4096, KS=5, STRIDE=2, DEPTH_VARIANT (Cin1=257), 12 depths.
// bf16-MFMA GEMM formulation with hi/lo split (3 mfma) for fp32-level accuracy.
// Activations channels-last rows: [b][t] -> 1024B = 256 bf16 hi | 256 bf16 lo.
// l stored fp32 channels-last rows (1024B); conv2 overwrites them with h in place.
// Round 7: 8-way sharded queue at (256,4). Round-6's (256,3) was a pure loss:
// VGPR only 64->72 (compiler spent nothing on prefetch) while resident waves
// fell 16->12/CU; conv1-d0 368->507us = exactly 4/3x -> the inner loop is
// latency-bound and hidden by WAVE-LEVEL overlap (m114), so occupancy is the
// latency-hiding budget, not registers. Revert to (256,4); keep the shard
// (R4 vs R2 isolates shard at equal occupancy; R4 vs R3 isolates occupancy).
// Shard q (blockIdx.x&7) owns items == q mod 8 of the x-major heavy-first
// order, counters 128B apart: same greedy balance, 1/8 the per-line pop
// traffic (R2's single counter serialized ~25K pops ~ 500us across the 23
// non-d0 dispatches).

typedef __attribute__((ext_vector_type(8))) __bf16 bf16x8;
typedef __attribute__((ext_vector_type(4))) float f32x4;

union U16B { uint4 u; bf16x8 b; };
__device__ __forceinline__ bf16x8 as_bf16x8(uint4 u) { U16B x; x.u = u; return x.b; }

__device__ __forceinline__ unsigned short bf_hi_bits(float x) {
    union { __bf16 b; unsigned short s; } u; u.b = (__bf16)x; return u.s;
}
__device__ __forceinline__ float bf_hi_f(float x) { return (float)(__bf16)x; }

#define MFMA(a, b, c) __builtin_amdgcn_mfma_f32_16x16x32_bf16(a, b, c, 0, 0, 0)

// ---------------- setup: finish_depth + stable argsort rank + queue zero ----
// ctrs: 24 kernel slots x 8 shards x 32 ints (128B shard stride) = 6144 ints.
__global__ void setup_kernel(const int* __restrict__ N0, int* __restrict__ rankfd,
                             int* __restrict__ ctrs) {
    __shared__ int fd_s[64];
    int b = threadIdx.x;
    for (int i = b; i < 24 * 256; i += 64) ctrs[i] = 0;
    int n = N0[b];
    int d = 0;
    while ((1 << (d + 1)) < n) ++d;   // first d with N0 <= 2^(d+1)
    fd_s[b] = d;
    __syncthreads();
    int myfd = fd_s[b];
    int r = 0;
    for (int i = 0; i < 64; ++i) {
        int f = fd_s[i];
        r += (f < myfd || (f == myfd && i < b)) ? 1 : 0;
    }
    rankfd[b] = r;
    rankfd[64 + b] = myfd;
}

// ------------- prepack: weights into MFMA A-fragment order, hi/lo ----------
// W*[chunk][ot][lane][j]; chunk = k*8+cc (c = cc*32 + (lane>>4)*8 + j),
// oc = ot*16 + (lane&15). conv1: OT=32 (512 oc), conv2: OT=16.
__global__ void prepack_kernel(const float* __restrict__ w1, const float* __restrict__ w2,
                               unsigned short* __restrict__ Whi1, unsigned short* __restrict__ Wlo1,
                               unsigned short* __restrict__ Whi2, unsigned short* __restrict__ Wlo2,
                               float* __restrict__ wd1, float* __restrict__ wsum1) {
    const int T1 = 40 * 32 * 512;
    const int T2 = 40 * 16 * 512;
    int id = blockIdx.x * 256 + threadIdx.x;
    if (id < T1) {
        int chunk = id >> 14;
        int rem = id & 16383;
        int ot = rem >> 9;
        int rem2 = rem & 511;
        int l = rem2 >> 3, j = rem2 & 7;
        int k = chunk >> 3, cc = chunk & 7;
        int oc = ot * 16 + (l & 15);
        int c = cc * 32 + (l >> 4) * 8 + j;
        float wv = w1[oc * 1285 + c * 5 + k];
        Whi1[id] = bf_hi_bits(wv);
        Wlo1[id] = bf_hi_bits(wv - bf_hi_f(wv));
    } else if (id < T1 + T2) {
        int base = id - T1;
        int chunk = base >> 13;
        int rem = base & 8191;
        int ot = rem >> 9;
        int rem2 = rem & 511;
        int l = rem2 >> 3, j = rem2 & 7;
        int k = chunk >> 3, cc = chunk & 7;
        int oc = ot * 16 + (l & 15);
        int c = cc * 32 + (l >> 4) * 8 + j;
        float wv = w2[oc * 1280 + c * 5 + k];
        Whi2[base] = bf_hi_bits(wv);
        Wlo2[base] = bf_hi_bits(wv - bf_hi_f(wv));
    } else if (id < T1 + T2 + 512) {
        int oc = id - T1 - T2;         // depth-channel weights (c = 256)
        float s = 0.f;
        for (int k = 0; k < 5; ++k) {
            float wv = w1[oc * 1285 + 1280 + k];
            wd1[oc * 5 + k] = wv;
            s += wv;
        }
        wsum1[oc] = s;
    }
}

// ---- transpose h [B][256][4096] fp32 (masked) -> channels-last hi/lo rows ----
__global__ __launch_bounds__(256, 4)
void transpose_kernel(const float* __restrict__ h, const int* __restrict__ N0,
                      char* __restrict__ H) {
    __shared__ unsigned short sm[2 * 64 * 140];   // 35840 B
    const int tid = threadIdx.x;
    const int b = blockIdx.z;
    const int c0 = blockIdx.y * 64;
    const int t0 = blockIdx.x * 128;
    const int n0 = N0[b];
    const int lane32 = tid & 31;
    // read phase
    for (int it = 0; it < 8; ++it) {
        int cl = (tid >> 5) * 8 + it;
        const float* src = h + ((size_t)(b * 256 + c0 + cl)) * 4096 + t0 + lane32 * 4;
        float4 v = *(const float4*)src;
        int gt = t0 + lane32 * 4;
        float f[4] = {v.x, v.y, v.z, v.w};
        ushort4 hi, lo;
        unsigned short* hp = &hi.x;
        unsigned short* lp = &lo.x;
#pragma unroll
        for (int e = 0; e < 4; ++e) {
            float x = (gt + e < n0) ? f[e] : 0.f;
            float xh = bf_hi_f(x);
            hp[e] = bf_hi_bits(x);
            lp[e] = bf_hi_bits(x - xh);
        }
        *(ushort4*)(&sm[cl * 140 + lane32 * 4]) = hi;
        *(ushort4*)(&sm[8960 + cl * 140 + lane32 * 4]) = lo;
    }
    __syncthreads();
    // write phase
    const int sub = tid & 7;
    const int rowp = tid >> 3;
    for (int rep = 0; rep < 8; ++rep) {
        int idx = rowp + 32 * rep;      // 0..255
        int tl = idx >> 1;
        int plane = idx & 1;
        union { unsigned short s[8]; uint4 u; } pk;
#pragma unroll
        for (int j = 0; j < 8; ++j)
            pk.s[j] = sm[plane * 8960 + (sub * 8 + j) * 140 + tl];
        char* dst = H + ((size_t)(b * 4096) + t0 + tl) * 1024 + plane * 512 + c0 * 2 + sub * 16;
        *(uint4*)dst = pk.u;
    }
}

// ---------------- conv1: lr = conv(hh_masked, w1, stride 2) ----------------
// Persistent, 8-way sharded queue: shard q = blockIdx.x&7 owns items == q mod 8
// of item = x*128 + y*64 + b (x-major: heavy-first). Tile 256 oc (y) x 64 t.
// K staged in 4 c-quarters (64 ch hi+lo, 132 rows x 256B = 33.8 KB LDS).
__global__ __launch_bounds__(256, 4)
void conv1_kernel(const char* __restrict__ Hin,
                  const unsigned short* __restrict__ Whi, const unsigned short* __restrict__ Wlo,
                  const float* __restrict__ b1, const float* __restrict__ wd1,
                  const float* __restrict__ wsum1, const int* __restrict__ N0,
                  float* __restrict__ Lout, char* __restrict__ Rout,
                  int T_in, int T_out, int depth, float logd,
                  int* __restrict__ ctr, int NI) {
    __shared__ __align__(16) char smem[132 * 256];
    __shared__ int s_it;
    const int tid = threadIdx.x;
    const int w = tid >> 6, l = tid & 63;
    const int qid = blockIdx.x & 7;
    int* my_ctr = ctr + qid * 32;       // 128B shard stride
    // staging decomposition: 16 chunks/row (8 hi + 8 lo of this quarter)
    const int sg_g8 = l & 7;
    const int sg_seg = (l >> 3) & 1;
    const int sg_rb0 = tid >> 4;        // 0..15

    for (;;) {
        if (tid == 0) s_it = qid + 8 * atomicAdd(my_ctr, 1);
        __syncthreads();
        const int item = s_it;
        __syncthreads();                 // WAR fence on s_it + cross-item LDS fence
        if (item >= NI) break;

        const int b = item & 63;
        const int y = (item >> 6) & 1;
        const int t0 = (item >> 7) * 64;
        const int n0 = N0[b];
        const int Nb = (n0 + (1 << depth) - 1) >> depth;   // input mask len
        const int Nn = (Nb + 1) >> 1;                      // output mask len

        if (t0 >= Nn) {
            if (y == 1) {   // zero r rows (conv2 reads them in its halo)
                int row = t0 + (tid >> 2);
                if (row < T_out) {
                    char* rp = Rout + ((size_t)(b * T_out) + row) * 1024 + (tid & 3) * 256;
                    uint4 z = make_uint4(0, 0, 0, 0);
#pragma unroll
                    for (int qq = 0; qq < 16; ++qq) *(uint4*)(rp + qq * 16) = z;
                }
            }
            continue;
        }

        f32x4 acc[4][4];
#pragma unroll
        for (int i = 0; i < 4; ++i)
#pragma unroll
            for (int j = 0; j < 4; ++j) acc[i][j] = f32x4{0.f, 0.f, 0.f, 0.f};

        const int base_p = 2 * t0 - 2;
        const int otg_base = y * 16 + w * 4;

#pragma unroll 1
        for (int q0 = 0; q0 < 4; ++q0) {
            if (q0) __syncthreads();
            for (int rb = sg_rb0; rb < 132; rb += 16) {
                int p = base_p + rb;
                uint4 v = make_uint4(0, 0, 0, 0);
                if (p >= 0 && p < T_in)
                    v = *(const uint4*)(Hin + ((size_t)(b * T_in) + p) * 1024 + sg_seg * 512 + q0 * 128 + sg_g8 * 16);
                int s = (rb >> 1) + (rb & 1) * 66;   // even/odd split for stride-2
                int phys = (sg_g8 ^ (s & 7)) | (sg_seg << 3);
                *(uint4*)(smem + s * 256 + phys * 16) = v;
            }
            __syncthreads();
#pragma unroll
            for (int k = 0; k < 5; ++k) {
#pragma unroll
                for (int ccl = 0; ccl < 2; ++ccl) {
                    const int chunk = k * 8 + q0 * 2 + ccl;
                    bf16x8 Bh[4], Bl[4];
#pragma unroll
                    for (int tt = 0; tt < 4; ++tt) {
                        int s = tt * 16 + (l & 15) + (k >> 1) + (k & 1) * 66;
                        int gB = ccl * 4 + (l >> 4);
                        int ph = gB ^ (s & 7);
                        Bh[tt] = as_bf16x8(*(const uint4*)(smem + s * 256 + ph * 16));
                        Bl[tt] = as_bf16x8(*(const uint4*)(smem + s * 256 + (ph | 8) * 16));
                    }
#pragma unroll
                    for (int ot = 0; ot < 4; ++ot) {
                        size_t aoff = ((size_t)(chunk * 32 + otg_base + ot)) * 512 + l * 8;
                        bf16x8 Ah = as_bf16x8(*(const uint4*)(Whi + aoff));
                        bf16x8 Al = as_bf16x8(*(const uint4*)(Wlo + aoff));
#pragma unroll
                        for (int tt = 0; tt < 4; ++tt) {
                            acc[ot][tt] = MFMA(Ah, Bh[tt], acc[ot][tt]);
                            acc[ot][tt] = MFMA(Ah, Bl[tt], acc[ot][tt]);
                            acc[ot][tt] = MFMA(Al, Bh[tt], acc[ot][tt]);
                        }
                    }
                }
            }
        }

        // ---- epilogue ----
        const int q = l >> 4;
        const int n = l & 15;
        const bool is_r = (y == 1);
#pragma unroll
        for (int ot = 0; ot < 4; ++ot) {
            const int ocg0 = (otg_base + ot) * 16 + q * 4;   // global oc (0..511)
            float4 bias = *(const float4*)(b1 + ocg0);
            float4 ws4 = *(const float4*)(wsum1 + ocg0);
#pragma unroll
            for (int tt = 0; tt < 4; ++tt) {
                int t = t0 + tt * 16 + n;
                if (t >= T_out) continue;
                float v0 = acc[ot][tt].x, v1 = acc[ot][tt].y, v2 = acc[ot][tt].z, v3 = acc[ot][tt].w;
                if (depth > 0) {   // depth channel (constant log1p(depth), masked)
                    if (t >= 1 && 2 * t + 2 < Nb) {
                        v0 += logd * ws4.x; v1 += logd * ws4.y;
                        v2 += logd * ws4.z; v3 += logd * ws4.w;
                    } else {
                        float ind[5];
#pragma unroll
                        for (int k = 0; k < 5; ++k) {
                            int p = 2 * t + k - 2;
                            ind[k] = (p >= 0 && p < Nb) ? logd : 0.f;
                        }
                        float sv[4] = {0.f, 0.f, 0.f, 0.f};
#pragma unroll
                        for (int j = 0; j < 4; ++j)
#pragma unroll
                            for (int k = 0; k < 5; ++k) sv[j] += ind[k] * wd1[(ocg0 + j) * 5 + k];
                        v0 += sv[0]; v1 += sv[1]; v2 += sv[2]; v3 += sv[3];
                    }
                }
                v0 += bias.x; v1 += bias.y; v2 += bias.z; v3 += bias.w;
                if (!is_r) {
                    float4 o; o.x = v0; o.y = v1; o.z = v2; o.w = v3;
                    *(float4*)(Lout + ((size_t)(b * T_out) + t) * 256 + ocg0) = o;
                } else {
                    bool live = (t < Nn);
                    float r0v = live ? fmaxf(v0, 0.f) : 0.f;
                    float r1v = live ? fmaxf(v1, 0.f) : 0.f;
                    float r2v = live ? fmaxf(v2, 0.f) : 0.f;
                    float r3v = live ? fmaxf(v3, 0.f) : 0.f;
                    int ocr = ocg0 - 256;
                    char* rrow = Rout + ((size_t)(b * T_out) + t) * 1024;
                    ushort4 H, L2;
                    H.x = bf_hi_bits(r0v); L2.x = bf_hi_bits(r0v - bf_hi_f(r0v));
                    H.y = bf_hi_bits(r1v); L2.y = bf_hi_bits(r1v - bf_hi_f(r1v));
                    H.z = bf_hi_bits(r2v); L2.z = bf_hi_bits(r2v - bf_hi_f(r2v));
                    H.w = bf_hi_bits(r3v); L2.w = bf_hi_bits(r3v - bf_hi_f(r3v));
                    *(ushort4*)(rrow + ocr * 2) = H;
                    *(ushort4*)(rrow + 512 + ocr * 2) = L2;
                }
            }
        }
    }
}

// ------------- conv2: h = relu(l + conv(r, w2, 1) + b2), in-place ----------
// Persistent, 8-way sharded queue over item = x*64 + b; tile 256 oc x 64 t;
// K staged in 2 c-halves (68 rows x 512B = 34.8 KB LDS).
__global__ __launch_bounds__(256, 4)
void conv2_kernel(const char* __restrict__ Rin,
                  const unsigned short* __restrict__ Whi, const unsigned short* __restrict__ Wlo,
                  const float* __restrict__ b2, const int* __restrict__ N0,
                  const int* __restrict__ rankfd, float* __restrict__ LH,
                  float* __restrict__ out, int T, int depth,
                  int* __restrict__ ctr, int NI) {
    __shared__ __align__(16) char smem[68 * 512];
    __shared__ int s_it;
    const int tid = threadIdx.x;
    const int w = tid >> 6, l = tid & 63;
    const int qid = blockIdx.x & 7;
    int* my_ctr = ctr + qid * 32;       // 128B shard stride
    const int sg_g16 = l & 15;
    const int sg_seg = (l >> 4) & 1;
    const int sg_rb0 = w * 2 + (l >> 5);

    for (;;) {
        if (tid == 0) s_it = qid + 8 * atomicAdd(my_ctr, 1);
        __syncthreads();
        const int item = s_it;
        __syncthreads();                 // WAR fence on s_it + cross-item LDS fence
        if (item >= NI) break;

        const int b = item & 63;
        const int t0 = (item >> 6) * 64;
        const int n0 = N0[b];
        const int Nn = (n0 + (1 << (depth + 1)) - 1) >> (depth + 1);

        if (t0 >= Nn) {   // h rows are zero here; next conv1 reads them
            int row = t0 + (tid >> 2);
            if (row < T) {
                char* hp = (char*)LH + ((size_t)(b * T) + row) * 1024 + (tid & 3) * 256;
                uint4 z = make_uint4(0, 0, 0, 0);
#pragma unroll
                for (int qq = 0; qq < 16; ++qq) *(uint4*)(hp + qq * 16) = z;
            }
            continue;
        }

        f32x4 acc[4][4];
#pragma unroll
        for (int i = 0; i < 4; ++i)
#pragma unroll
            for (int j = 0; j < 4; ++j) acc[i][j] = f32x4{0.f, 0.f, 0.f, 0.f};

#pragma unroll 1
        for (int hf = 0; hf < 2; ++hf) {
            if (hf) __syncthreads();
            for (int rb = sg_rb0; rb < 68; rb += 8) {
                int p = t0 - 2 + rb;
                uint4 v = make_uint4(0, 0, 0, 0);
                if (p >= 0 && p < T)
                    v = *(const uint4*)(Rin + ((size_t)(b * T) + p) * 1024 + sg_seg * 512 + hf * 256 + sg_g16 * 16);
                int phys = (sg_g16 ^ (rb & 7)) | (sg_seg << 4);
                *(uint4*)(smem + rb * 512 + phys * 16) = v;
            }
            __syncthreads();
#pragma unroll
            for (int k = 0; k < 5; ++k) {
#pragma unroll
                for (int cc = 0; cc < 4; ++cc) {
                    const int chunk = k * 8 + hf * 4 + cc;
                    bf16x8 Bh[4], Bl[4];
#pragma unroll
                    for (int tt = 0; tt < 4; ++tt) {
                        int s = tt * 16 + (l & 15) + k;
                        int gq = cc * 4 + (l >> 4);
                        int ph = gq ^ (s & 7);
                        Bh[tt] = as_bf16x8(*(const uint4*)(smem + s * 512 + ph * 16));
                        Bl[tt] = as_bf16x8(*(const uint4*)(smem + s * 512 + (ph | 16) * 16));
                    }
#pragma unroll
                    for (int ot = 0; ot < 4; ++ot) {
                        size_t aoff = ((size_t)(chunk * 16 + w * 4 + ot)) * 512 + l * 8;
                        bf16x8 Ah = as_bf16x8(*(const uint4*)(Whi + aoff));
                        bf16x8 Al = as_bf16x8(*(const uint4*)(Wlo + aoff));
#pragma unroll
                        for (int tt = 0; tt < 4; ++tt) {
                            acc[ot][tt] = MFMA(Ah, Bh[tt], acc[ot][tt]);
                            acc[ot][tt] = MFMA(Ah, Bl[tt], acc[ot][tt]);
                            acc[ot][tt] = MFMA(Al, Bh[tt], acc[ot][tt]);
                        }
                    }
                }
            }
        }

        // ---- epilogue: l + acc + bias, relu, mask, capture; barrier; in-place h ----
        const int q = l >> 4;
        const int n = l & 15;
        const int rk = rankfd[b];
        const int fd = rankfd[64 + b];
#pragma unroll
        for (int ot = 0; ot < 4; ++ot) {
            const int ocg0 = (w * 4 + ot) * 16 + q * 4;
            float4 bias = *(const float4*)(b2 + ocg0);
#pragma unroll
            for (int tt = 0; tt < 4; ++tt) {
                int t = t0 + tt * 16 + n;
                float v0 = 0.f, v1 = 0.f, v2 = 0.f, v3 = 0.f;
                if (t < T && t < Nn) {
                    float4 l4 = *(const float4*)(LH + ((size_t)(b * T) + t) * 256 + ocg0);
                    v0 = fmaxf(acc[ot][tt].x + l4.x + bias.x, 0.f);
                    v1 = fmaxf(acc[ot][tt].y + l4.y + bias.y, 0.f);
                    v2 = fmaxf(acc[ot][tt].z + l4.z + bias.z, 0.f);
                    v3 = fmaxf(acc[ot][tt].w + l4.w + bias.w, 0.f);
                    if (t == 0 && depth == fd) {
                        float4 o; o.x = v0; o.y = v1; o.z = v2; o.w = v3;
                        *(float4*)(out + rk * 256 + ocg0) = o;
                    }
                }
                acc[ot][tt] = f32x4{v0, v1, v2, v3};   // reuse acc as value buffer
            }
        }
        __syncthreads();   // all l-reads complete before in-place overwrite
#pragma unroll
        for (int ot = 0; ot < 4; ++ot) {
            const int ocg0 = (w * 4 + ot) * 16 + q * 4;
#pragma unroll
            for (int tt = 0; tt < 4; ++tt) {
                int t = t0 + tt * 16 + n;
                if (t >= T) continue;
                char* hrow = (char*)LH + ((size_t)(b * T) + t) * 1024;
                float v0 = acc[ot][tt].x, v1 = acc[ot][tt].y, v2 = acc[ot][tt].z, v3 = acc[ot][tt].w;
                ushort4 H, L2;
                H.x = bf_hi_bits(v0); L2.x = bf_hi_bits(v0 - bf_hi_f(v0));
                H.y = bf_hi_bits(v1); L2.y = bf_hi_bits(v1 - bf_hi_f(v1));
                H.z = bf_hi_bits(v2); L2.z = bf_hi_bits(v2 - bf_hi_f(v2));
                H.w = bf_hi_bits(v3); L2.w = bf_hi_bits(v3 - bf_hi_f(v3));
                *(ushort4*)(hrow + ocg0 * 2) = H;
                *(ushort4*)(hrow + 512 + ocg0 * 2) = L2;
            }
        }
    }
}

// --------------------------------- launch ----------------------------------
extern "C" void kernel_launch(void* const* d_in, const int* in_sizes, int n_in,
                              void* d_out, int out_size, void* d_ws, size_t ws_size,
                              hipStream_t stream) {
    const float* h  = (const float*)d_in[0];
    const int*   N0 = (const int*)d_in[1];
    const float* w1 = (const float*)d_in[2];
    const float* b1 = (const float*)d_in[3];
    const float* w2 = (const float*)d_in[4];
    const float* b2 = (const float*)d_in[5];
    float* out = (float*)d_out;

    char* ws = (char*)d_ws;
    size_t off = 0;
    auto alloc = [&](size_t bytes) -> void* {
        void* p = ws + off;
        off = (off + bytes + 255) & ~(size_t)255;
        return p;
    };
    int* rankfd            = (int*)alloc(512);
    float* wd1             = (float*)alloc(512 * 5 * 4);
    float* wsum1           = (float*)alloc(512 * 4);
    unsigned short* Whi1   = (unsigned short*)alloc((size_t)655360 * 2);
    unsigned short* Wlo1   = (unsigned short*)alloc((size_t)655360 * 2);
    unsigned short* Whi2   = (unsigned short*)alloc((size_t)327680 * 2);
    unsigned short* Wlo2   = (unsigned short*)alloc((size_t)327680 * 2);
    float* P1              = (float*)alloc((size_t)64 * 2048 * 1024);   // even-depth h rows
    char*  H4096           = (char*)alloc((size_t)64 * 4096 * 1024);   // depth-0 input
    float* P0              = (float*)H4096;   // alias: H4096 dead after d0 conv1
    char*  R               = (char*)alloc((size_t)64 * 2048 * 1024);
    int* ctrs              = (int*)alloc((size_t)24 * 256 * 4);   // 24 slots x 8 shards x 128B
    (void)ws_size;

    setup_kernel<<<1, 64, 0, stream>>>(N0, rankfd, ctrs);
    {
        int total = 655360 + 327680 + 512;
        prepack_kernel<<<(total + 255) / 256, 256, 0, stream>>>(w1, w2, Whi1, Wlo1, Whi2, Wlo2, wd1, wsum1);
    }
    transpose_kernel<<<dim3(32, 4, 64), 256, 0, stream>>>(h, N0, H4096);

    int T_in = 4096;
    for (int d = 0; d < 12; ++d) {
        int To = T_in >> 1;
        float* LH = (d & 1) ? P0 : P1;
        const char* Hin = (d == 0) ? (const char*)H4096 : (const char*)((d & 1) ? P1 : P0);
        float logd = log1pf((float)d);
        int gx = (To + 63) / 64;
        int NI1 = gx * 128;                       // x-major: heavy-first, light tail
        int NI2 = gx * 64;
        int g1 = NI1 < 1024 ? NI1 : 1024;         // persistent blocks
        int g2 = NI2 < 1024 ? NI2 : 1024;
        conv1_kernel<<<g1, 256, 0, stream>>>(Hin, Whi1, Wlo1, b1, wd1, wsum1, N0,
                                             LH, R, T_in, To, d, logd,
                                             ctrs + (2 * d) * 256, NI1);
        conv2_kernel<<<g2, 256, 0, stream>>>(R, Whi2, Wlo2, b2, N0, rankfd, LH, out, To, d,
                                             ctrs + (2 * d + 1) * 256, NI2);
        T_in = To;
    }
}

// Round 5
// 2621.120 us; speedup vs baseline: 1.2874x; 1.2813x over previous
//
#include <hip/hip_runtime.h>
#include <cmath>
#include <cstdint>

// B=64, NH=256, T=4096, KS=5, STRIDE=2, DEPTH_VARIANT (Cin1=257), 12 depths.
// bf16-MFMA GEMM formulation with hi/lo split (3 mfma) for fp32-level accuracy.
// Activations channels-last rows: [b][t] -> 1024B = 256 bf16 hi | 256 bf16 lo.
// l stored fp32 channels-last rows (1024B); conv2 overwrites them with h in place.
// Round 8: static x-rotation, queue REMOVED. The 2x2 (R2/R3/R4) showed: the
// atomic queue wins d0 (368us) but costs ~500us across the 23 other dispatches;
// mod-8 sharding degenerated to a batch partition (item%8 == b%8) and made
// balance WORSE (453us). Root fix without atomics: under any periodic-256 CP
// dispatch, CU c gets ids {c+256k}; for grid (gx,2,64) that pins blockIdx.x
// and enumerates k = b>>2. Rotating x_eff = (x + 5*(b>>2)) & (gx-1) (odd
// stride -> full coverage mod 2^n) gives each CU a spread of t-positions:
// heavy count per CU ~9+-2 instead of {0|16} -> makespan ~3 rounds not 4.
// Zero overhead, bijective per batch, baseline code path otherwise.

typedef __attribute__((ext_vector_type(8))) __bf16 bf16x8;
typedef __attribute__((ext_vector_type(4))) float f32x4;

union U16B { uint4 u; bf16x8 b; };
__device__ __forceinline__ bf16x8 as_bf16x8(uint4 u) { U16B x; x.u = u; return x.b; }

__device__ __forceinline__ unsigned short bf_hi_bits(float x) {
    union { __bf16 b; unsigned short s; } u; u.b = (__bf16)x; return u.s;
}
__device__ __forceinline__ float bf_hi_f(float x) { return (float)(__bf16)x; }

#define MFMA(a, b, c) __builtin_amdgcn_mfma_f32_16x16x32_bf16(a, b, c, 0, 0, 0)

// ---------------- setup: finish_depth + stable argsort rank ----------------
__global__ void setup_kernel(const int* __restrict__ N0, int* __restrict__ rankfd) {
    __shared__ int fd_s[64];
    int b = threadIdx.x;
    int n = N0[b];
    int d = 0;
    while ((1 << (d + 1)) < n) ++d;   // first d with N0 <= 2^(d+1)
    fd_s[b] = d;
    __syncthreads();
    int myfd = fd_s[b];
    int r = 0;
    for (int i = 0; i < 64; ++i) {
        int f = fd_s[i];
        r += (f < myfd || (f == myfd && i < b)) ? 1 : 0;
    }
    rankfd[b] = r;
    rankfd[64 + b] = myfd;
}

// ------------- prepack: weights into MFMA A-fragment order, hi/lo ----------
// W*[chunk][ot][lane][j]; chunk = k*8+cc (c = cc*32 + (lane>>4)*8 + j),
// oc = ot*16 + (lane&15). conv1: OT=32 (512 oc), conv2: OT=16.
__global__ void prepack_kernel(const float* __restrict__ w1, const float* __restrict__ w2,
                               unsigned short* __restrict__ Whi1, unsigned short* __restrict__ Wlo1,
                               unsigned short* __restrict__ Whi2, unsigned short* __restrict__ Wlo2,
                               float* __restrict__ wd1, float* __restrict__ wsum1) {
    const int T1 = 40 * 32 * 512;
    const int T2 = 40 * 16 * 512;
    int id = blockIdx.x * 256 + threadIdx.x;
    if (id < T1) {
        int chunk = id >> 14;
        int rem = id & 16383;
        int ot = rem >> 9;
        int rem2 = rem & 511;
        int l = rem2 >> 3, j = rem2 & 7;
        int k = chunk >> 3, cc = chunk & 7;
        int oc = ot * 16 + (l & 15);
        int c = cc * 32 + (l >> 4) * 8 + j;
        float wv = w1[oc * 1285 + c * 5 + k];
        Whi1[id] = bf_hi_bits(wv);
        Wlo1[id] = bf_hi_bits(wv - bf_hi_f(wv));
    } else if (id < T1 + T2) {
        int base = id - T1;
        int chunk = base >> 13;
        int rem = base & 8191;
        int ot = rem >> 9;
        int rem2 = rem & 511;
        int l = rem2 >> 3, j = rem2 & 7;
        int k = chunk >> 3, cc = chunk & 7;
        int oc = ot * 16 + (l & 15);
        int c = cc * 32 + (l >> 4) * 8 + j;
        float wv = w2[oc * 1280 + c * 5 + k];
        Whi2[base] = bf_hi_bits(wv);
        Wlo2[base] = bf_hi_bits(wv - bf_hi_f(wv));
    } else if (id < T1 + T2 + 512) {
        int oc = id - T1 - T2;         // depth-channel weights (c = 256)
        float s = 0.f;
        for (int k = 0; k < 5; ++k) {
            float wv = w1[oc * 1285 + 1280 + k];
            wd1[oc * 5 + k] = wv;
            s += wv;
        }
        wsum1[oc] = s;
    }
}

// ---- transpose h [B][256][4096] fp32 (masked) -> channels-last hi/lo rows ----
__global__ __launch_bounds__(256, 4)
void transpose_kernel(const float* __restrict__ h, const int* __restrict__ N0,
                      char* __restrict__ H) {
    __shared__ unsigned short sm[2 * 64 * 140];   // 35840 B
    const int tid = threadIdx.x;
    const int b = blockIdx.z;
    const int c0 = blockIdx.y * 64;
    const int t0 = blockIdx.x * 128;
    const int n0 = N0[b];
    const int lane32 = tid & 31;
    // read phase
    for (int it = 0; it < 8; ++it) {
        int cl = (tid >> 5) * 8 + it;
        const float* src = h + ((size_t)(b * 256 + c0 + cl)) * 4096 + t0 + lane32 * 4;
        float4 v = *(const float4*)src;
        int gt = t0 + lane32 * 4;
        float f[4] = {v.x, v.y, v.z, v.w};
        ushort4 hi, lo;
        unsigned short* hp = &hi.x;
        unsigned short* lp = &lo.x;
#pragma unroll
        for (int e = 0; e < 4; ++e) {
            float x = (gt + e < n0) ? f[e] : 0.f;
            float xh = bf_hi_f(x);
            hp[e] = bf_hi_bits(x);
            lp[e] = bf_hi_bits(x - xh);
        }
        *(ushort4*)(&sm[cl * 140 + lane32 * 4]) = hi;
        *(ushort4*)(&sm[8960 + cl * 140 + lane32 * 4]) = lo;
    }
    __syncthreads();
    // write phase
    const int sub = tid & 7;
    const int rowp = tid >> 3;
    for (int rep = 0; rep < 8; ++rep) {
        int idx = rowp + 32 * rep;      // 0..255
        int tl = idx >> 1;
        int plane = idx & 1;
        union { unsigned short s[8]; uint4 u; } pk;
#pragma unroll
        for (int j = 0; j < 8; ++j)
            pk.s[j] = sm[plane * 8960 + (sub * 8 + j) * 140 + tl];
        char* dst = H + ((size_t)(b * 4096) + t0 + tl) * 1024 + plane * 512 + c0 * 2 + sub * 16;
        *(uint4*)dst = pk.u;
    }
}

// ---------------- conv1: lr = conv(hh_masked, w1, stride 2) ----------------
// Block 256 thr = 4 waves; block tile 256 oc (y in {0,1}) x 64 t; wave 64oc x 64t.
// x-rotation: t-tile = (blockIdx.x + 5*(b>>2)) & (gx-1) decorrelates heavy
// status from the CU's periodic dispatch class.
// K staged in 4 c-quarters (64 ch hi+lo, 132 rows x 256B = 33.8 KB LDS).
__global__ __launch_bounds__(256, 4)
void conv1_kernel(const char* __restrict__ Hin,
                  const unsigned short* __restrict__ Whi, const unsigned short* __restrict__ Wlo,
                  const float* __restrict__ b1, const float* __restrict__ wd1,
                  const float* __restrict__ wsum1, const int* __restrict__ N0,
                  float* __restrict__ Lout, char* __restrict__ Rout,
                  int T_in, int T_out, int depth, float logd) {
    __shared__ __align__(16) char smem[132 * 256];
    const int tid = threadIdx.x;
    const int w = tid >> 6, l = tid & 63;
    const int b = blockIdx.z;
    const int x_eff = (int)((blockIdx.x + 5u * (blockIdx.z >> 2)) & (gridDim.x - 1));
    const int t0 = x_eff * 64;
    const int n0 = N0[b];
    const int Nb = (n0 + (1 << depth) - 1) >> depth;   // input mask len
    const int Nn = (Nb + 1) >> 1;                      // output mask len

    if (t0 >= Nn) {
        if (blockIdx.y == 1) {   // zero r rows (conv2 reads them in its halo)
            int row = t0 + (tid >> 2);
            if (row < T_out) {
                char* rp = Rout + ((size_t)(b * T_out) + row) * 1024 + (tid & 3) * 256;
                uint4 z = make_uint4(0, 0, 0, 0);
#pragma unroll
                for (int qq = 0; qq < 16; ++qq) *(uint4*)(rp + qq * 16) = z;
            }
        }
        return;
    }

    f32x4 acc[4][4];
#pragma unroll
    for (int i = 0; i < 4; ++i)
#pragma unroll
        for (int j = 0; j < 4; ++j) acc[i][j] = f32x4{0.f, 0.f, 0.f, 0.f};

    const int base_p = 2 * t0 - 2;
    const int otg_base = blockIdx.y * 16 + w * 4;

    // staging decomposition: 16 chunks/row (8 hi + 8 lo of this quarter)
    const int sg_g8 = l & 7;
    const int sg_seg = (l >> 3) & 1;
    const int sg_rb0 = tid >> 4;        // 0..15

#pragma unroll 1
    for (int q0 = 0; q0 < 4; ++q0) {
        if (q0) __syncthreads();
        for (int rb = sg_rb0; rb < 132; rb += 16) {
            int p = base_p + rb;
            uint4 v = make_uint4(0, 0, 0, 0);
            if (p >= 0 && p < T_in)
                v = *(const uint4*)(Hin + ((size_t)(b * T_in) + p) * 1024 + sg_seg * 512 + q0 * 128 + sg_g8 * 16);
            int s = (rb >> 1) + (rb & 1) * 66;   // even/odd split for stride-2
            int phys = (sg_g8 ^ (s & 7)) | (sg_seg << 3);
            *(uint4*)(smem + s * 256 + phys * 16) = v;
        }
        __syncthreads();
#pragma unroll
        for (int k = 0; k < 5; ++k) {
#pragma unroll
            for (int ccl = 0; ccl < 2; ++ccl) {
                const int chunk = k * 8 + q0 * 2 + ccl;
                bf16x8 Bh[4], Bl[4];
#pragma unroll
                for (int tt = 0; tt < 4; ++tt) {
                    int s = tt * 16 + (l & 15) + (k >> 1) + (k & 1) * 66;
                    int gB = ccl * 4 + (l >> 4);
                    int ph = gB ^ (s & 7);
                    Bh[tt] = as_bf16x8(*(const uint4*)(smem + s * 256 + ph * 16));
                    Bl[tt] = as_bf16x8(*(const uint4*)(smem + s * 256 + (ph | 8) * 16));
                }
#pragma unroll
                for (int ot = 0; ot < 4; ++ot) {
                    size_t aoff = ((size_t)(chunk * 32 + otg_base + ot)) * 512 + l * 8;
                    bf16x8 Ah = as_bf16x8(*(const uint4*)(Whi + aoff));
                    bf16x8 Al = as_bf16x8(*(const uint4*)(Wlo + aoff));
#pragma unroll
                    for (int tt = 0; tt < 4; ++tt) {
                        acc[ot][tt] = MFMA(Ah, Bh[tt], acc[ot][tt]);
                        acc[ot][tt] = MFMA(Ah, Bl[tt], acc[ot][tt]);
                        acc[ot][tt] = MFMA(Al, Bh[tt], acc[ot][tt]);
                    }
                }
            }
        }
    }

    // ---- epilogue ----
    const int q = l >> 4;
    const int n = l & 15;
    const bool is_r = (blockIdx.y == 1);
#pragma unroll
    for (int ot = 0; ot < 4; ++ot) {
        const int ocg0 = (otg_base + ot) * 16 + q * 4;   // global oc (0..511)
        float4 bias = *(const float4*)(b1 + ocg0);
        float4 ws4 = *(const float4*)(wsum1 + ocg0);
#pragma unroll
        for (int tt = 0; tt < 4; ++tt) {
            int t = t0 + tt * 16 + n;
            if (t >= T_out) continue;
            float v0 = acc[ot][tt].x, v1 = acc[ot][tt].y, v2 = acc[ot][tt].z, v3 = acc[ot][tt].w;
            if (depth > 0) {   // depth channel (constant log1p(depth), masked)
                if (t >= 1 && 2 * t + 2 < Nb) {
                    v0 += logd * ws4.x; v1 += logd * ws4.y;
                    v2 += logd * ws4.z; v3 += logd * ws4.w;
                } else {
                    float ind[5];
#pragma unroll
                    for (int k = 0; k < 5; ++k) {
                        int p = 2 * t + k - 2;
                        ind[k] = (p >= 0 && p < Nb) ? logd : 0.f;
                    }
                    float sv[4] = {0.f, 0.f, 0.f, 0.f};
#pragma unroll
                    for (int j = 0; j < 4; ++j)
#pragma unroll
                        for (int k = 0; k < 5; ++k) sv[j] += ind[k] * wd1[(ocg0 + j) * 5 + k];
                    v0 += sv[0]; v1 += sv[1]; v2 += sv[2]; v3 += sv[3];
                }
            }
            v0 += bias.x; v1 += bias.y; v2 += bias.z; v3 += bias.w;
            if (!is_r) {
                float4 o; o.x = v0; o.y = v1; o.z = v2; o.w = v3;
                *(float4*)(Lout + ((size_t)(b * T_out) + t) * 256 + ocg0) = o;
            } else {
                bool live = (t < Nn);
                float r0v = live ? fmaxf(v0, 0.f) : 0.f;
                float r1v = live ? fmaxf(v1, 0.f) : 0.f;
                float r2v = live ? fmaxf(v2, 0.f) : 0.f;
                float r3v = live ? fmaxf(v3, 0.f) : 0.f;
                int ocr = ocg0 - 256;
                char* rrow = Rout + ((size_t)(b * T_out) + t) * 1024;
                ushort4 H, L2;
                H.x = bf_hi_bits(r0v); L2.x = bf_hi_bits(r0v - bf_hi_f(r0v));
                H.y = bf_hi_bits(r1v); L2.y = bf_hi_bits(r1v - bf_hi_f(r1v));
                H.z = bf_hi_bits(r2v); L2.z = bf_hi_bits(r2v - bf_hi_f(r2v));
                H.w = bf_hi_bits(r3v); L2.w = bf_hi_bits(r3v - bf_hi_f(r3v));
                *(ushort4*)(rrow + ocr * 2) = H;
                *(ushort4*)(rrow + 512 + ocr * 2) = L2;
            }
        }
    }
}

// ------------- conv2: h = relu(l + conv(r, w2, 1) + b2), in-place ----------
// Block 256 oc x 64 t; same x-rotation; K staged in 2 c-halves
// (68 rows x 512B = 34.8 KB LDS).
__global__ __launch_bounds__(256, 4)
void conv2_kernel(const char* __restrict__ Rin,
                  const unsigned short* __restrict__ Whi, const unsigned short* __restrict__ Wlo,
                  const float* __restrict__ b2, const int* __restrict__ N0,
                  const int* __restrict__ rankfd, float* __restrict__ LH,
                  float* __restrict__ out, int T, int depth) {
    __shared__ __align__(16) char smem[68 * 512];
    const int tid = threadIdx.x;
    const int w = tid >> 6, l = tid & 63;
    const int b = blockIdx.z;
    const int x_eff = (int)((blockIdx.x + 5u * (blockIdx.z >> 2)) & (gridDim.x - 1));
    const int t0 = x_eff * 64;
    const int n0 = N0[b];
    const int Nn = (n0 + (1 << (depth + 1)) - 1) >> (depth + 1);

    if (t0 >= Nn) {   // h rows are zero here; next conv1 reads them
        int row = t0 + (tid >> 2);
        if (row < T) {
            char* hp = (char*)LH + ((size_t)(b * T) + row) * 1024 + (tid & 3) * 256;
            uint4 z = make_uint4(0, 0, 0, 0);
#pragma unroll
            for (int qq = 0; qq < 16; ++qq) *(uint4*)(hp + qq * 16) = z;
        }
        return;
    }

    f32x4 acc[4][4];
#pragma unroll
    for (int i = 0; i < 4; ++i)
#pragma unroll
        for (int j = 0; j < 4; ++j) acc[i][j] = f32x4{0.f, 0.f, 0.f, 0.f};

    const int sg_g16 = l & 15;
    const int sg_seg = (l >> 4) & 1;
    const int sg_rb0 = w * 2 + (l >> 5);

#pragma unroll 1
    for (int hf = 0; hf < 2; ++hf) {
        if (hf) __syncthreads();
        for (int rb = sg_rb0; rb < 68; rb += 8) {
            int p = t0 - 2 + rb;
            uint4 v = make_uint4(0, 0, 0, 0);
            if (p >= 0 && p < T)
                v = *(const uint4*)(Rin + ((size_t)(b * T) + p) * 1024 + sg_seg * 512 + hf * 256 + sg_g16 * 16);
            int phys = (sg_g16 ^ (rb & 7)) | (sg_seg << 4);
            *(uint4*)(smem + rb * 512 + phys * 16) = v;
        }
        __syncthreads();
#pragma unroll
        for (int k = 0; k < 5; ++k) {
#pragma unroll
            for (int cc = 0; cc < 4; ++cc) {
                const int chunk = k * 8 + hf * 4 + cc;
                bf16x8 Bh[4], Bl[4];
#pragma unroll
                for (int tt = 0; tt < 4; ++tt) {
                    int s = tt * 16 + (l & 15) + k;
                    int gq = cc * 4 + (l >> 4);
                    int ph = gq ^ (s & 7);
                    Bh[tt] = as_bf16x8(*(const uint4*)(smem + s * 512 + ph * 16));
                    Bl[tt] = as_bf16x8(*(const uint4*)(smem + s * 512 + (ph | 16) * 16));
                }
#pragma unroll
                for (int ot = 0; ot < 4; ++ot) {
                    size_t aoff = ((size_t)(chunk * 16 + w * 4 + ot)) * 512 + l * 8;
                    bf16x8 Ah = as_bf16x8(*(const uint4*)(Whi + aoff));
                    bf16x8 Al = as_bf16x8(*(const uint4*)(Wlo + aoff));
#pragma unroll
                    for (int tt = 0; tt < 4; ++tt) {
                        acc[ot][tt] = MFMA(Ah, Bh[tt], acc[ot][tt]);
                        acc[ot][tt] = MFMA(Ah, Bl[tt], acc[ot][tt]);
                        acc[ot][tt] = MFMA(Al, Bh[tt], acc[ot][tt]);
                    }
                }
            }
        }
    }

    // ---- epilogue: l + acc + bias, relu, mask, capture; barrier; in-place h ----
    const int q = l >> 4;
    const int n = l & 15;
    const int rk = rankfd[b];
    const int fd = rankfd[64 + b];
#pragma unroll
    for (int ot = 0; ot < 4; ++ot) {
        const int ocg0 = (w * 4 + ot) * 16 + q * 4;
        float4 bias = *(const float4*)(b2 + ocg0);
#pragma unroll
        for (int tt = 0; tt < 4; ++tt) {
            int t = t0 + tt * 16 + n;
            float v0 = 0.f, v1 = 0.f, v2 = 0.f, v3 = 0.f;
            if (t < T && t < Nn) {
                float4 l4 = *(const float4*)(LH + ((size_t)(b * T) + t) * 256 + ocg0);
                v0 = fmaxf(acc[ot][tt].x + l4.x + bias.x, 0.f);
                v1 = fmaxf(acc[ot][tt].y + l4.y + bias.y, 0.f);
                v2 = fmaxf(acc[ot][tt].z + l4.z + bias.z, 0.f);
                v3 = fmaxf(acc[ot][tt].w + l4.w + bias.w, 0.f);
                if (t == 0 && depth == fd) {
                    float4 o; o.x = v0; o.y = v1; o.z = v2; o.w = v3;
                    *(float4*)(out + rk * 256 + ocg0) = o;
                }
            }
            acc[ot][tt] = f32x4{v0, v1, v2, v3};   // reuse acc as value buffer
        }
    }
    __syncthreads();   // all l-reads complete before in-place overwrite
#pragma unroll
    for (int ot = 0; ot < 4; ++ot) {
        const int ocg0 = (w * 4 + ot) * 16 + q * 4;
#pragma unroll
        for (int tt = 0; tt < 4; ++tt) {
            int t = t0 + tt * 16 + n;
            if (t >= T) continue;
            char* hrow = (char*)LH + ((size_t)(b * T) + t) * 1024;
            float v0 = acc[ot][tt].x, v1 = acc[ot][tt].y, v2 = acc[ot][tt].z, v3 = acc[ot][tt].w;
            ushort4 H, L2;
            H.x = bf_hi_bits(v0); L2.x = bf_hi_bits(v0 - bf_hi_f(v0));
            H.y = bf_hi_bits(v1); L2.y = bf_hi_bits(v1 - bf_hi_f(v1));
            H.z = bf_hi_bits(v2); L2.z = bf_hi_bits(v2 - bf_hi_f(v2));
            H.w = bf_hi_bits(v3); L2.w = bf_hi_bits(v3 - bf_hi_f(v3));
            *(ushort4*)(hrow + ocg0 * 2) = H;
            *(ushort4*)(hrow + 512 + ocg0 * 2) = L2;
        }
    }
}

// --------------------------------- launch ----------------------------------
extern "C" void kernel_launch(void* const* d_in, const int* in_sizes, int n_in,
                              void* d_out, int out_size, void* d_ws, size_t ws_size,
                              hipStream_t stream) {
    const float* h  = (const float*)d_in[0];
    const int*   N0 = (const int*)d_in[1];
    const float* w1 = (const float*)d_in[2];
    const float* b1 = (const float*)d_in[3];
    const float* w2 = (const float*)d_in[4];
    const float* b2 = (const float*)d_in[5];
    float* out = (float*)d_out;

    char* ws = (char*)d_ws;
    size_t off = 0;
    auto alloc = [&](size_t bytes) -> void* {
        void* p = ws + off;
        off = (off + bytes + 255) & ~(size_t)255;
        return p;
    };
    int* rankfd            = (int*)alloc(512);
    float* wd1             = (float*)alloc(512 * 5 * 4);
    float* wsum1           = (float*)alloc(512 * 4);
    unsigned short* Whi1   = (unsigned short*)alloc((size_t)655360 * 2);
    unsigned short* Wlo1   = (unsigned short*)alloc((size_t)655360 * 2);
    unsigned short* Whi2   = (unsigned short*)alloc((size_t)327680 * 2);
    unsigned short* Wlo2   = (unsigned short*)alloc((size_t)327680 * 2);
    float* P1              = (float*)alloc((size_t)64 * 2048 * 1024);   // even-depth h rows
    char*  H4096           = (char*)alloc((size_t)64 * 4096 * 1024);   // depth-0 input
    float* P0              = (float*)H4096;   // alias: H4096 dead after d0 conv1
    char*  R               = (char*)alloc((size_t)64 * 2048 * 1024);
    (void)ws_size;

    setup_kernel<<<1, 64, 0, stream>>>(N0, rankfd);
    {
        int total = 655360 + 327680 + 512;
        prepack_kernel<<<(total + 255) / 256, 256, 0, stream>>>(w1, w2, Whi1, Wlo1, Whi2, Wlo2, wd1, wsum1);
    }
    transpose_kernel<<<dim3(32, 4, 64), 256, 0, stream>>>(h, N0, H4096);

    int T_in = 4096;
    for (int d = 0; d < 12; ++d) {
        int To = T_in >> 1;
        float* LH = (d & 1) ? P0 : P1;
        const char* Hin = (d == 0) ? (const char*)H4096 : (const char*)((d & 1) ? P1 : P0);
        float logd = log1pf((float)d);
        dim3 g1((To + 63) / 64, 2, 64);
        conv1_kernel<<<g1, 256, 0, stream>>>(Hin, Whi1, Wlo1, b1, wd1, wsum1, N0,
                                             LH, R, T_in, To, d, logd);
        dim3 g2((To + 63) / 64, 1, 64);
        conv2_kernel<<<g2, 256, 0, stream>>>(R, Whi2, Wlo2, b2, N0, rankfd, LH, out, To, d);
        T_in = To;
    }
}

// Round 7
// 2560.116 us; speedup vs baseline: 1.3180x; 1.0238x over previous
//
#include <hip/hip_runtime.h>
#include <cmath>
#include <cstdint>

// B=64, NH=256, T=4096, KS=5, STRIDE=2, DEPTH_VARIANT (Cin1=257), 12 depths.
// bf16-MFMA GEMM formulation with hi/lo split (3 mfma) for fp32-level accuracy.
// Activations channels-last rows: [b][t] -> 1024B = 256 bf16 hi | 256 bf16 lo.
// l stored fp32 channels-last rows (1024B); conv2 overwrites them with h in place.
// Round 9b: resubmit of round 9 (died to infra container failure; audit found
// no OOB/hang path: reads guarded to [0,n0), LDS writes <= 33790 < 33792,
// layout equivalence d0-fused vs packed verified). TRANSPOSE KERNEL ELIMINATED:
// R8 profile showed transpose_kernel as #1 dispatch (1003us, MfmaUtil 0,
// 401 GB/s, 2.9e7 LDS bank conflicts) and it was redundant traffic (256 MB
// write + 256 MB re-read). conv1-d0 now stages DIRECTLY from channel-major
// fp32 h, converting to hi/lo bf16 into the identical swizzled smem layout
// (per-element t<n0 masking replicates _seq_mask).
// Keeps R8's x-rotation: x_eff = (x + 5*(b>>2)) & (gx-1) decorrelates heavy
// tiles from the CP's periodic block->CU classes (d0 conv1 500->364us).

typedef __attribute__((ext_vector_type(8))) __bf16 bf16x8;
typedef __attribute__((ext_vector_type(4))) float f32x4;

union U16B { uint4 u; bf16x8 b; };
__device__ __forceinline__ bf16x8 as_bf16x8(uint4 u) { U16B x; x.u = u; return x.b; }

__device__ __forceinline__ unsigned short bf_hi_bits(float x) {
    union { __bf16 b; unsigned short s; } u; u.b = (__bf16)x; return u.s;
}
__device__ __forceinline__ float bf_hi_f(float x) { return (float)(__bf16)x; }

#define MFMA(a, b, c) __builtin_amdgcn_mfma_f32_16x16x32_bf16(a, b, c, 0, 0, 0)

// ---------------- setup: finish_depth + stable argsort rank ----------------
__global__ void setup_kernel(const int* __restrict__ N0, int* __restrict__ rankfd) {
    __shared__ int fd_s[64];
    int b = threadIdx.x;
    int n = N0[b];
    int d = 0;
    while ((1 << (d + 1)) < n) ++d;   // first d with N0 <= 2^(d+1)
    fd_s[b] = d;
    __syncthreads();
    int myfd = fd_s[b];
    int r = 0;
    for (int i = 0; i < 64; ++i) {
        int f = fd_s[i];
        r += (f < myfd || (f == myfd && i < b)) ? 1 : 0;
    }
    rankfd[b] = r;
    rankfd[64 + b] = myfd;
}

// ------------- prepack: weights into MFMA A-fragment order, hi/lo ----------
// W*[chunk][ot][lane][j]; chunk = k*8+cc (c = cc*32 + (lane>>4)*8 + j),
// oc = ot*16 + (lane&15). conv1: OT=32 (512 oc), conv2: OT=16.
__global__ void prepack_kernel(const float* __restrict__ w1, const float* __restrict__ w2,
                               unsigned short* __restrict__ Whi1, unsigned short* __restrict__ Wlo1,
                               unsigned short* __restrict__ Whi2, unsigned short* __restrict__ Wlo2,
                               float* __restrict__ wd1, float* __restrict__ wsum1) {
    const int T1 = 40 * 32 * 512;
    const int T2 = 40 * 16 * 512;
    int id = blockIdx.x * 256 + threadIdx.x;
    if (id < T1) {
        int chunk = id >> 14;
        int rem = id & 16383;
        int ot = rem >> 9;
        int rem2 = rem & 511;
        int l = rem2 >> 3, j = rem2 & 7;
        int k = chunk >> 3, cc = chunk & 7;
        int oc = ot * 16 + (l & 15);
        int c = cc * 32 + (l >> 4) * 8 + j;
        float wv = w1[oc * 1285 + c * 5 + k];
        Whi1[id] = bf_hi_bits(wv);
        Wlo1[id] = bf_hi_bits(wv - bf_hi_f(wv));
    } else if (id < T1 + T2) {
        int base = id - T1;
        int chunk = base >> 13;
        int rem = base & 8191;
        int ot = rem >> 9;
        int rem2 = rem & 511;
        int l = rem2 >> 3, j = rem2 & 7;
        int k = chunk >> 3, cc = chunk & 7;
        int oc = ot * 16 + (l & 15);
        int c = cc * 32 + (l >> 4) * 8 + j;
        float wv = w2[oc * 1280 + c * 5 + k];
        Whi2[base] = bf_hi_bits(wv);
        Wlo2[base] = bf_hi_bits(wv - bf_hi_f(wv));
    } else if (id < T1 + T2 + 512) {
        int oc = id - T1 - T2;         // depth-channel weights (c = 256)
        float s = 0.f;
        for (int k = 0; k < 5; ++k) {
            float wv = w1[oc * 1285 + 1280 + k];
            wd1[oc * 5 + k] = wv;
            s += wv;
        }
        wsum1[oc] = s;
    }
}

// ---------------- conv1: lr = conv(hh_masked, w1, stride 2) ----------------
// Block 256 thr = 4 waves; block tile 256 oc (y in {0,1}) x 64 t; wave 64oc x 64t.
// depth 0: stage from fp32 channel-major h directly (fused transpose+mask+
// hi/lo convert). depth>0: stage packed 1024B rows from Hin.
// K staged in 4 c-quarters (64 ch hi+lo, 132 rows x 256B = 33.8 KB LDS).
__global__ __launch_bounds__(256, 4)
void conv1_kernel(const float* __restrict__ h0, const char* __restrict__ Hin,
                  const unsigned short* __restrict__ Whi, const unsigned short* __restrict__ Wlo,
                  const float* __restrict__ b1, const float* __restrict__ wd1,
                  const float* __restrict__ wsum1, const int* __restrict__ N0,
                  float* __restrict__ Lout, char* __restrict__ Rout,
                  int T_in, int T_out, int depth, float logd) {
    __shared__ __align__(16) char smem[132 * 256];
    const int tid = threadIdx.x;
    const int w = tid >> 6, l = tid & 63;
    const int b = blockIdx.z;
    const int x_eff = (int)((blockIdx.x + 5u * (blockIdx.z >> 2)) & (gridDim.x - 1));
    const int t0 = x_eff * 64;
    const int n0 = N0[b];
    const int Nb = (n0 + (1 << depth) - 1) >> depth;   // input mask len
    const int Nn = (Nb + 1) >> 1;                      // output mask len

    if (t0 >= Nn) {
        if (blockIdx.y == 1) {   // zero r rows (conv2 reads them in its halo)
            int row = t0 + (tid >> 2);
            if (row < T_out) {
                char* rp = Rout + ((size_t)(b * T_out) + row) * 1024 + (tid & 3) * 256;
                uint4 z = make_uint4(0, 0, 0, 0);
#pragma unroll
                for (int qq = 0; qq < 16; ++qq) *(uint4*)(rp + qq * 16) = z;
            }
        }
        return;
    }

    f32x4 acc[4][4];
#pragma unroll
    for (int i = 0; i < 4; ++i)
#pragma unroll
        for (int j = 0; j < 4; ++j) acc[i][j] = f32x4{0.f, 0.f, 0.f, 0.f};

    const int base_p = 2 * t0 - 2;
    const int otg_base = blockIdx.y * 16 + w * 4;

    // packed-row staging decomposition (depth>0): 16 chunks/row (8 hi + 8 lo)
    const int sg_g8 = l & 7;
    const int sg_seg = (l >> 3) & 1;
    const int sg_rb0 = tid >> 4;        // 0..15

    // fused fp32 staging decomposition (depth==0): 32 thr per channel-octet
    const int f_oct = tid >> 5;         // 0..7
    const int f_g = tid & 31;
    const int f_cl = f_g >> 2;          // channel within octet
    const int f_i0 = f_g & 3;           // float4 phase
    const int al = base_p & ~3;         // 4-aligned cover of [base_p, base_p+132)

#pragma unroll 1
    for (int q0 = 0; q0 < 4; ++q0) {
        if (q0) __syncthreads();
        if (depth == 0) {
            const float* hch = h0 + ((size_t)(b * 256 + q0 * 64 + f_oct * 8 + f_cl)) * 4096;
#pragma unroll 1
            for (int m = 0; m < 9; ++m) {
                int p4 = al + 4 * (f_i0 + 4 * m);
                float fe0 = 0.f, fe1 = 0.f, fe2 = 0.f, fe3 = 0.f;
                if (p4 >= 0 && p4 < n0) {
                    float4 v = *(const float4*)(hch + p4);
                    fe0 = v.x;
                    fe1 = (p4 + 1 < n0) ? v.y : 0.f;
                    fe2 = (p4 + 2 < n0) ? v.z : 0.f;
                    fe3 = (p4 + 3 < n0) ? v.w : 0.f;
                }
                float fe[4] = {fe0, fe1, fe2, fe3};
#pragma unroll
                for (int e = 0; e < 4; ++e) {
                    int rb = p4 + e - base_p;
                    if (rb >= 0 && rb < 132) {
                        int s = (rb >> 1) + (rb & 1) * 66;
                        int byte_hi = s * 256 + ((f_oct ^ (s & 7)) * 16) + f_cl * 2;
                        float x = fe[e];
                        float xh = bf_hi_f(x);
                        *(unsigned short*)(smem + byte_hi) = bf_hi_bits(x);
                        *(unsigned short*)(smem + byte_hi + 128) = bf_hi_bits(x - xh);
                    }
                }
            }
        } else {
            for (int rb = sg_rb0; rb < 132; rb += 16) {
                int p = base_p + rb;
                uint4 v = make_uint4(0, 0, 0, 0);
                if (p >= 0 && p < T_in)
                    v = *(const uint4*)(Hin + ((size_t)(b * T_in) + p) * 1024 + sg_seg * 512 + q0 * 128 + sg_g8 * 16);
                int s = (rb >> 1) + (rb & 1) * 66;   // even/odd split for stride-2
                int phys = (sg_g8 ^ (s & 7)) | (sg_seg << 3);
                *(uint4*)(smem + s * 256 + phys * 16) = v;
            }
        }
        __syncthreads();
#pragma unroll
        for (int k = 0; k < 5; ++k) {
#pragma unroll
            for (int ccl = 0; ccl < 2; ++ccl) {
                const int chunk = k * 8 + q0 * 2 + ccl;
                bf16x8 Bh[4], Bl[4];
#pragma unroll
                for (int tt = 0; tt < 4; ++tt) {
                    int s = tt * 16 + (l & 15) + (k >> 1) + (k & 1) * 66;
                    int gB = ccl * 4 + (l >> 4);
                    int ph = gB ^ (s & 7);
                    Bh[tt] = as_bf16x8(*(const uint4*)(smem + s * 256 + ph * 16));
                    Bl[tt] = as_bf16x8(*(const uint4*)(smem + s * 256 + (ph | 8) * 16));
                }
#pragma unroll
                for (int ot = 0; ot < 4; ++ot) {
                    size_t aoff = ((size_t)(chunk * 32 + otg_base + ot)) * 512 + l * 8;
                    bf16x8 Ah = as_bf16x8(*(const uint4*)(Whi + aoff));
                    bf16x8 Al = as_bf16x8(*(const uint4*)(Wlo + aoff));
#pragma unroll
                    for (int tt = 0; tt < 4; ++tt) {
                        acc[ot][tt] = MFMA(Ah, Bh[tt], acc[ot][tt]);
                        acc[ot][tt] = MFMA(Ah, Bl[tt], acc[ot][tt]);
                        acc[ot][tt] = MFMA(Al, Bh[tt], acc[ot][tt]);
                    }
                }
            }
        }
    }

    // ---- epilogue ----
    const int q = l >> 4;
    const int n = l & 15;
    const bool is_r = (blockIdx.y == 1);
#pragma unroll
    for (int ot = 0; ot < 4; ++ot) {
        const int ocg0 = (otg_base + ot) * 16 + q * 4;   // global oc (0..511)
        float4 bias = *(const float4*)(b1 + ocg0);
        float4 ws4 = *(const float4*)(wsum1 + ocg0);
#pragma unroll
        for (int tt = 0; tt < 4; ++tt) {
            int t = t0 + tt * 16 + n;
            if (t >= T_out) continue;
            float v0 = acc[ot][tt].x, v1 = acc[ot][tt].y, v2 = acc[ot][tt].z, v3 = acc[ot][tt].w;
            if (depth > 0) {   // depth channel (constant log1p(depth), masked)
                if (t >= 1 && 2 * t + 2 < Nb) {
                    v0 += logd * ws4.x; v1 += logd * ws4.y;
                    v2 += logd * ws4.z; v3 += logd * ws4.w;
                } else {
                    float ind[5];
#pragma unroll
                    for (int k = 0; k < 5; ++k) {
                        int p = 2 * t + k - 2;
                        ind[k] = (p >= 0 && p < Nb) ? logd : 0.f;
                    }
                    float sv[4] = {0.f, 0.f, 0.f, 0.f};
#pragma unroll
                    for (int j = 0; j < 4; ++j)
#pragma unroll
                        for (int k = 0; k < 5; ++k) sv[j] += ind[k] * wd1[(ocg0 + j) * 5 + k];
                    v0 += sv[0]; v1 += sv[1]; v2 += sv[2]; v3 += sv[3];
                }
            }
            v0 += bias.x; v1 += bias.y; v2 += bias.z; v3 += bias.w;
            if (!is_r) {
                float4 o; o.x = v0; o.y = v1; o.z = v2; o.w = v3;
                *(float4*)(Lout + ((size_t)(b * T_out) + t) * 256 + ocg0) = o;
            } else {
                bool live = (t < Nn);
                float r0v = live ? fmaxf(v0, 0.f) : 0.f;
                float r1v = live ? fmaxf(v1, 0.f) : 0.f;
                float r2v = live ? fmaxf(v2, 0.f) : 0.f;
                float r3v = live ? fmaxf(v3, 0.f) : 0.f;
                int ocr = ocg0 - 256;
                char* rrow = Rout + ((size_t)(b * T_out) + t) * 1024;
                ushort4 H, L2;
                H.x = bf_hi_bits(r0v); L2.x = bf_hi_bits(r0v - bf_hi_f(r0v));
                H.y = bf_hi_bits(r1v); L2.y = bf_hi_bits(r1v - bf_hi_f(r1v));
                H.z = bf_hi_bits(r2v); L2.z = bf_hi_bits(r2v - bf_hi_f(r2v));
                H.w = bf_hi_bits(r3v); L2.w = bf_hi_bits(r3v - bf_hi_f(r3v));
                *(ushort4*)(rrow + ocr * 2) = H;
                *(ushort4*)(rrow + 512 + ocr * 2) = L2;
            }
        }
    }
}

// ------------- conv2: h = relu(l + conv(r, w2, 1) + b2), in-place ----------
// Block 256 oc x 64 t; same x-rotation; K staged in 2 c-halves
// (68 rows x 512B = 34.8 KB LDS).
__global__ __launch_bounds__(256, 4)
void conv2_kernel(const char* __restrict__ Rin,
                  const unsigned short* __restrict__ Whi, const unsigned short* __restrict__ Wlo,
                  const float* __restrict__ b2, const int* __restrict__ N0,
                  const int* __restrict__ rankfd, float* __restrict__ LH,
                  float* __restrict__ out, int T, int depth) {
    __shared__ __align__(16) char smem[68 * 512];
    const int tid = threadIdx.x;
    const int w = tid >> 6, l = tid & 63;
    const int b = blockIdx.z;
    const int x_eff = (int)((blockIdx.x + 5u * (blockIdx.z >> 2)) & (gridDim.x - 1));
    const int t0 = x_eff * 64;
    const int n0 = N0[b];
    const int Nn = (n0 + (1 << (depth + 1)) - 1) >> (depth + 1);

    if (t0 >= Nn) {   // h rows are zero here; next conv1 reads them
        int row = t0 + (tid >> 2);
        if (row < T) {
            char* hp = (char*)LH + ((size_t)(b * T) + row) * 1024 + (tid & 3) * 256;
            uint4 z = make_uint4(0, 0, 0, 0);
#pragma unroll
            for (int qq = 0; qq < 16; ++qq) *(uint4*)(hp + qq * 16) = z;
        }
        return;
    }

    f32x4 acc[4][4];
#pragma unroll
    for (int i = 0; i < 4; ++i)
#pragma unroll
        for (int j = 0; j < 4; ++j) acc[i][j] = f32x4{0.f, 0.f, 0.f, 0.f};

    const int sg_g16 = l & 15;
    const int sg_seg = (l >> 4) & 1;
    const int sg_rb0 = w * 2 + (l >> 5);

#pragma unroll 1
    for (int hf = 0; hf < 2; ++hf) {
        if (hf) __syncthreads();
        for (int rb = sg_rb0; rb < 68; rb += 8) {
            int p = t0 - 2 + rb;
            uint4 v = make_uint4(0, 0, 0, 0);
            if (p >= 0 && p < T)
                v = *(const uint4*)(Rin + ((size_t)(b * T) + p) * 1024 + sg_seg * 512 + hf * 256 + sg_g16 * 16);
            int phys = (sg_g16 ^ (rb & 7)) | (sg_seg << 4);
            *(uint4*)(smem + rb * 512 + phys * 16) = v;
        }
        __syncthreads();
#pragma unroll
        for (int k = 0; k < 5; ++k) {
#pragma unroll
            for (int cc = 0; cc < 4; ++cc) {
                const int chunk = k * 8 + hf * 4 + cc;
                bf16x8 Bh[4], Bl[4];
#pragma unroll
                for (int tt = 0; tt < 4; ++tt) {
                    int s = tt * 16 + (l & 15) + k;
                    int gq = cc * 4 + (l >> 4);
                    int ph = gq ^ (s & 7);
                    Bh[tt] = as_bf16x8(*(const uint4*)(smem + s * 512 + ph * 16));
                    Bl[tt] = as_bf16x8(*(const uint4*)(smem + s * 512 + (ph | 16) * 16));
                }
#pragma unroll
                for (int ot = 0; ot < 4; ++ot) {
                    size_t aoff = ((size_t)(chunk * 16 + w * 4 + ot)) * 512 + l * 8;
                    bf16x8 Ah = as_bf16x8(*(const uint4*)(Whi + aoff));
                    bf16x8 Al = as_bf16x8(*(const uint4*)(Wlo + aoff));
#pragma unroll
                    for (int tt = 0; tt < 4; ++tt) {
                        acc[ot][tt] = MFMA(Ah, Bh[tt], acc[ot][tt]);
                        acc[ot][tt] = MFMA(Ah, Bl[tt], acc[ot][tt]);
                        acc[ot][tt] = MFMA(Al, Bh[tt], acc[ot][tt]);
                    }
                }
            }
        }
    }

    // ---- epilogue: l + acc + bias, relu, mask, capture; barrier; in-place h ----
    const int q = l >> 4;
    const int n = l & 15;
    const int rk = rankfd[b];
    const int fd = rankfd[64 + b];
#pragma unroll
    for (int ot = 0; ot < 4; ++ot) {
        const int ocg0 = (w * 4 + ot) * 16 + q * 4;
        float4 bias = *(const float4*)(b2 + ocg0);
#pragma unroll
        for (int tt = 0; tt < 4; ++tt) {
            int t = t0 + tt * 16 + n;
            float v0 = 0.f, v1 = 0.f, v2 = 0.f, v3 = 0.f;
            if (t < T && t < Nn) {
                float4 l4 = *(const float4*)(LH + ((size_t)(b * T) + t) * 256 + ocg0);
                v0 = fmaxf(acc[ot][tt].x + l4.x + bias.x, 0.f);
                v1 = fmaxf(acc[ot][tt].y + l4.y + bias.y, 0.f);
                v2 = fmaxf(acc[ot][tt].z + l4.z + bias.z, 0.f);
                v3 = fmaxf(acc[ot][tt].w + l4.w + bias.w, 0.f);
                if (t == 0 && depth == fd) {
                    float4 o; o.x = v0; o.y = v1; o.z = v2; o.w = v3;
                    *(float4*)(out + rk * 256 + ocg0) = o;
                }
            }
            acc[ot][tt] = f32x4{v0, v1, v2, v3};   // reuse acc as value buffer
        }
    }
    __syncthreads();   // all l-reads complete before in-place overwrite
#pragma unroll
    for (int ot = 0; ot < 4; ++ot) {
        const int ocg0 = (w * 4 + ot) * 16 + q * 4;
#pragma unroll
        for (int tt = 0; tt < 4; ++tt) {
            int t = t0 + tt * 16 + n;
            if (t >= T) continue;
            char* hrow = (char*)LH + ((size_t)(b * T) + t) * 1024;
            float v0 = acc[ot][tt].x, v1 = acc[ot][tt].y, v2 = acc[ot][tt].z, v3 = acc[ot][tt].w;
            ushort4 H, L2;
            H.x = bf_hi_bits(v0); L2.x = bf_hi_bits(v0 - bf_hi_f(v0));
            H.y = bf_hi_bits(v1); L2.y = bf_hi_bits(v1 - bf_hi_f(v1));
            H.z = bf_hi_bits(v2); L2.z = bf_hi_bits(v2 - bf_hi_f(v2));
            H.w = bf_hi_bits(v3); L2.w = bf_hi_bits(v3 - bf_hi_f(v3));
            *(ushort4*)(hrow + ocg0 * 2) = H;
            *(ushort4*)(hrow + 512 + ocg0 * 2) = L2;
        }
    }
}

// --------------------------------- launch ----------------------------------
extern "C" void kernel_launch(void* const* d_in, const int* in_sizes, int n_in,
                              void* d_out, int out_size, void* d_ws, size_t ws_size,
                              hipStream_t stream) {
    const float* h  = (const float*)d_in[0];
    const int*   N0 = (const int*)d_in[1];
    const float* w1 = (const float*)d_in[2];
    const float* b1 = (const float*)d_in[3];
    const float* w2 = (const float*)d_in[4];
    const float* b2 = (const float*)d_in[5];
    float* out = (float*)d_out;

    char* ws = (char*)d_ws;
    size_t off = 0;
    auto alloc = [&](size_t bytes) -> void* {
        void* p = ws + off;
        off = (off + bytes + 255) & ~(size_t)255;
        return p;
    };
    int* rankfd            = (int*)alloc(512);
    float* wd1             = (float*)alloc(512 * 5 * 4);
    float* wsum1           = (float*)alloc(512 * 4);
    unsigned short* Whi1   = (unsigned short*)alloc((size_t)655360 * 2);
    unsigned short* Wlo1   = (unsigned short*)alloc((size_t)655360 * 2);
    unsigned short* Whi2   = (unsigned short*)alloc((size_t)327680 * 2);
    unsigned short* Wlo2   = (unsigned short*)alloc((size_t)327680 * 2);
    float* P1              = (float*)alloc((size_t)64 * 2048 * 1024);   // even-depth h rows
    char*  P0c             = (char*)alloc((size_t)64 * 4096 * 1024);    // odd-depth h rows (oversized; ex-H4096)
    float* P0              = (float*)P0c;
    char*  R               = (char*)alloc((size_t)64 * 2048 * 1024);
    (void)ws_size;

    setup_kernel<<<1, 64, 0, stream>>>(N0, rankfd);
    {
        int total = 655360 + 327680 + 512;
        prepack_kernel<<<(total + 255) / 256, 256, 0, stream>>>(w1, w2, Whi1, Wlo1, Whi2, Wlo2, wd1, wsum1);
    }

    int T_in = 4096;
    for (int d = 0; d < 12; ++d) {
        int To = T_in >> 1;
        float* LH = (d & 1) ? P0 : P1;
        const char* Hin = (const char*)((d & 1) ? P1 : P0);   // unused at d==0
        float logd = log1pf((float)d);
        dim3 g1((To + 63) / 64, 2, 64);
        conv1_kernel<<<g1, 256, 0, stream>>>(h, Hin, Whi1, Wlo1, b1, wd1, wsum1, N0,
                                             LH, R, T_in, To, d, logd);
        dim3 g2((To + 63) / 64, 1, 64);
        conv2_kernel<<<g2, 256, 0, stream>>>(R, Whi2, Wlo2, b2, N0, rankfd, LH, out, To, d);
        T_in = To;
    }
}